// Round 1
// baseline (82.355 us; speedup 1.0000x reference)
//
#include <hip/hip_runtime.h>

// Problem constants (from reference)
#define NS   1000        // N_SAMPLES
#define NB   32          // batch
#define NK   27          // cluster channels
#define KP   28          // padded K (for float4)
#define NCG  3           // guidance channels
#define HW   65536       // 256*256
// ALPHA=0.5, BETA=0.15, GAMMA=0.05, W1=10, W2=3, SHIFT=0
// sim = 10*exp(-cd/1.0 - gd/0.3) + 3*exp(-cd/0.1)

// ws layout (floats):
//   selc [NB][NS][KP]  : 32*1000*28 = 896000
//   selg [NB][NS][4]   : 128000   (offset 896000)
//   cf   [NS][2]       : 2000     (offset 1024000)
#define OFF_SELG 896000
#define OFF_CF   1024000

__global__ void crf_gather(const float* __restrict__ guidance,
                           const float* __restrict__ clusters,
                           const int* __restrict__ coords,
                           float* __restrict__ ws) {
    int tid = blockIdx.x * blockDim.x + threadIdx.x;
    if (tid >= NB * NS) return;
    int n = tid / NS;
    int i = tid - n * NS;
    int r = coords[i];        // coords[0][i]
    int c = coords[NS + i];   // coords[1][i]
    long pix = (long)r * 256 + c;

    const float* cl = clusters + (long)n * NK * HW + pix;
    float* selc = ws + ((long)n * NS + i) * KP;
    #pragma unroll
    for (int k = 0; k < NK; ++k) selc[k] = cl[(long)k * HW];
    selc[27] = 0.0f;

    const float* gu = guidance + (long)n * NCG * HW + pix;
    float* selg = ws + OFF_SELG + ((long)n * NS + i) * 4;
    selg[0] = gu[0];
    selg[1] = gu[HW];
    selg[2] = gu[2 * HW];
    selg[3] = 0.0f;

    if (n == 0) {
        float* cf = ws + OFF_CF + i * 2;
        cf[0] = (float)r;
        cf[1] = (float)c;
    }
}

#define RA     25          // a-rows per block
#define NCHUNK 40          // NS / RA

__global__ __launch_bounds__(256) void crf_main(const float* __restrict__ ws,
                                                float* __restrict__ out) {
    __shared__ __align__(16) float s_selc[RA][KP];
    __shared__ __align__(16) float s_selg[RA][4];
    __shared__ __align__(8)  float s_cf[RA][2];

    const int bid = blockIdx.x;
    const int n = bid / NCHUNK;
    const int a0 = (bid - n * NCHUNK) * RA;
    const int t = threadIdx.x;

    const float* selc = ws;
    const float* selg = ws + OFF_SELG;
    const float* cf   = ws + OFF_CF;

    // stage a-tile into LDS (coalesced)
    for (int idx = t; idx < RA * KP; idx += 256) {
        int a = idx / KP, k = idx - a * KP;
        s_selc[a][k] = selc[((long)n * NS + a0 + a) * KP + k];
    }
    for (int idx = t; idx < RA * 4; idx += 256) {
        int a = idx >> 2, c2 = idx & 3;
        s_selg[a][c2] = selg[((long)n * NS + a0 + a) * 4 + c2];
    }
    for (int idx = t; idx < RA * 2; idx += 256) {
        int a = idx >> 1, c2 = idx & 1;
        s_cf[a][c2] = cf[(a0 + a) * 2 + c2];
    }
    __syncthreads();

    for (int cc = 0; cc < 4; ++cc) {
        const int b = cc * 256 + t;
        if (b >= NS) break;

        // per-thread column data in registers
        float4 cb[7];
        const float4* pc = (const float4*)(selc + ((long)n * NS + b) * KP);
        #pragma unroll
        for (int j = 0; j < 7; ++j) cb[j] = pc[j];
        const float4 gb = *(const float4*)(selg + ((long)n * NS + b) * 4);
        const float2 xb = *(const float2*)(cf + (long)b * 2);

        float* po = out + ((long)n * NS + a0) * NS + b;

        #pragma unroll 5
        for (int a = 0; a < RA; ++a) {
            const float4* pa = (const float4*)s_selc[a];
            float dot = 0.0f;
            #pragma unroll
            for (int j = 0; j < 7; ++j) {
                float4 va = pa[j];
                dot += va.x * cb[j].x;
                dot += va.y * cb[j].y;
                dot += va.z * cb[j].z;
                dot += va.w * cb[j].w;
            }
            float g0 = s_selg[a][0] - gb.x;
            float g1 = s_selg[a][1] - gb.y;
            float g2 = s_selg[a][2] - gb.z;
            float gd = g0 * g0 + g1 * g1 + g2 * g2;
            float dr = s_cf[a][0] - xb.x;
            float dc = s_cf[a][1] - xb.y;
            float cd = dr * dr + dc * dc;
            float s = 10.0f * __expf(-cd - gd * (1.0f / 0.3f))
                    +  3.0f * __expf(-10.0f * cd);
            po[(long)a * NS] = -dot * s;
        }
    }
}

extern "C" void kernel_launch(void* const* d_in, const int* in_sizes, int n_in,
                              void* d_out, int out_size, void* d_ws, size_t ws_size,
                              hipStream_t stream) {
    const float* guidance = (const float*)d_in[0];
    const float* clusters = (const float*)d_in[1];
    const int*   coords   = (const int*)d_in[2];
    float* out = (float*)d_out;
    float* ws  = (float*)d_ws;

    // gather: one thread per (n, i)
    {
        int total = NB * NS;
        int blocks = (total + 255) / 256;
        crf_gather<<<blocks, 256, 0, stream>>>(guidance, clusters, coords, ws);
    }
    // main: one block per (n, a-chunk)
    {
        int blocks = NB * NCHUNK;
        crf_main<<<blocks, 256, 0, stream>>>(ws, out);
    }
}